// Round 4
// baseline (1516.284 us; speedup 1.0000x reference)
//
#include <hip/hip_runtime.h>

#define N_NODES  100000
#define N_EDGES  1600000
#define NODE_DIM 64
#define EDGE_DIM 16
#define HIDDEN   64
#define NBKT     1563            // ceil(N_NODES/64)
#define NB1 ((N_NODES + 255) / 256)

typedef __bf16 bf16x8 __attribute__((ext_vector_type(8)));
typedef unsigned short u16x8 __attribute__((ext_vector_type(8)));
typedef unsigned short u16x4 __attribute__((ext_vector_type(4)));
typedef float f32x4 __attribute__((ext_vector_type(4)));

__device__ __forceinline__ unsigned short f2bf(float f) {
    unsigned int u = __float_as_uint(f);
    u += 0x7FFFu + ((u >> 16) & 1u);          // RNE
    return (unsigned short)(u >> 16);
}

__device__ __forceinline__ float bf2f(unsigned short s) {
    return __uint_as_float((unsigned int)s << 16);
}

__device__ __forceinline__ bf16x8 lds_frag(const unsigned short* p) {
    return __builtin_bit_cast(bf16x8, *(const u16x8*)p);
}

__device__ __forceinline__ void cvt16v(unsigned short* dst,
                                       float4 f0, float4 f1, float4 f2, float4 f3) {
    u16x8 p0, p1;
    p0[0]=f2bf(f0.x); p0[1]=f2bf(f0.y); p0[2]=f2bf(f0.z); p0[3]=f2bf(f0.w);
    p0[4]=f2bf(f1.x); p0[5]=f2bf(f1.y); p0[6]=f2bf(f1.z); p0[7]=f2bf(f1.w);
    p1[0]=f2bf(f2.x); p1[1]=f2bf(f2.y); p1[2]=f2bf(f2.z); p1[3]=f2bf(f2.w);
    p1[4]=f2bf(f3.x); p1[5]=f2bf(f3.y); p1[6]=f2bf(f3.z); p1[7]=f2bf(f3.w);
    *(u16x8*)dst       = p0;
    *(u16x8*)(dst + 8) = p1;
}

__device__ __forceinline__ void cvt4v(unsigned short* dst, float4 f) {
    u16x4 p;
    p[0]=f2bf(f.x); p[1]=f2bf(f.y); p[2]=f2bf(f.z); p[3]=f2bf(f.w);
    *(u16x4*)dst = p;
}

// ---- prep: bf16 weights (transposed) + bf16 copy of x + bucket histogram ----
__global__ void prep_kernel(const float* __restrict__ W1, const float* __restrict__ W2,
                            const float* __restrict__ Wu, const float* __restrict__ x,
                            const int* __restrict__ ei,
                            unsigned short* __restrict__ W1t,   // [64][160], k>=144 zero
                            unsigned short* __restrict__ W2t,   // [64][64]
                            unsigned short* __restrict__ Wut,   // [64][128]
                            unsigned short* __restrict__ xb,    // [N+64][64] bf16
                            int* __restrict__ bhist)
{
    int t = blockIdx.x * 256 + threadIdx.x;
    int stride = gridDim.x * 256;
    for (int i = t; i < N_NODES * 64 / 4; i += stride) {
        float4 f = ((const float4*)x)[i];
        cvt4v(&xb[i * 4], f);
    }
    for (int e = t; e < N_EDGES; e += stride)
        atomicAdd(&bhist[ei[N_EDGES + e] >> 6], 1);
    for (int i = t; i < 64 * 160; i += stride) {
        int n = i / 160, k = i % 160;
        W1t[i] = (k < 144) ? f2bf(W1[k * 64 + n]) : (unsigned short)0;
    }
    for (int i = t; i < 64 * 64; i += stride) {
        int n = i / 64, k = i % 64;
        W2t[i] = f2bf(W2[k * 64 + n]);
    }
    for (int i = t; i < 64 * 128; i += stride) {
        int n = i / 128, k = i % 128;
        Wut[i] = f2bf(Wu[k * 64 + n]);
    }
}

// ---- single-block scan of 1563 bucket counts (Hillis-Steele, double buffer) ----
#define SCN 2048
__global__ void bscan_kernel(const int* __restrict__ bhist,
                             int* __restrict__ bofs, int* __restrict__ bcur) {
    __shared__ int s0[SCN], s1[SCN];
    const int t = threadIdx.x;                 // 1024 threads
    for (int i = t; i < SCN; i += 1024) s0[i] = (i < NBKT) ? bhist[i] : 0;
    __syncthreads();
    int* src = s0; int* dst = s1;
    for (int off = 1; off < SCN; off <<= 1) {
        for (int i = t; i < SCN; i += 1024)
            dst[i] = (i >= off) ? src[i] + src[i - off] : src[i];
        __syncthreads();
        int* tmp = src; src = dst; dst = tmp;
    }
    for (int i = t; i < NBKT; i += 1024) {
        int e = (i > 0) ? src[i - 1] : 0;      // exclusive
        bofs[i] = e; bcur[i] = e;
    }
    if (t == 0) bofs[NBKT] = N_EDGES;
}

// ---- bucket fill: scatter (src|dstoff) meta + bf16 ea row into bucket order ----
__global__ void bfill_kernel(const int* __restrict__ ei, const float* __restrict__ ea,
                             int* __restrict__ bcur,
                             unsigned int* __restrict__ meta,     // [E+128]
                             unsigned short* __restrict__ ea_s)   // [E+128][16] bf16
{
    int idx = blockIdx.x * 256 + threadIdx.x;
    int stride = gridDim.x * 256;
    if (idx < 128) meta[N_EDGES + idx] = 0;                      // zero pad
    if (idx < 256) {                                             // zero ea_s pad
        u16x8 z = {0,0,0,0,0,0,0,0};
        ((u16x8*)(ea_s + (size_t)N_EDGES * 16))[idx] = z;
    }
    for (int e = idx; e < N_EDGES; e += stride) {
        int s = ei[e];
        int d = ei[N_EDGES + e];
        int pos = atomicAdd(&bcur[d >> 6], 1);
        meta[pos] = ((unsigned int)(d & 63) << 17) | (unsigned int)s;
        const float4* pe = (const float4*)(ea + (size_t)e * 16);
        cvt16v(ea_s + (size_t)pos * 16, pe[0], pe[1], pe[2], pe[3]);
    }
}

// LDS strides (elems): Ain 168; W1 164; H 72; node-A 136; Acc stride 65 f32.
#define SA   168
#define SW1  164
#define SH   72
#define NSA  136
#define SACC 65
#define WAVE_LDS (16*SA*2 + 16*SH*2)   // 7680 B per wave

// ---- fused per-bucket: message GEMMs + fp32 LDS accumulate + node update ----
__global__ __launch_bounds__(256, 2) void bagg_kernel(
    const unsigned short* __restrict__ xb,
    const unsigned short* __restrict__ ea_s,
    const unsigned int*  __restrict__ meta,
    const int* __restrict__ bofs,
    const unsigned short* __restrict__ W1t,
    const unsigned short* __restrict__ W2t,
    const float* __restrict__ b1,
    const float* __restrict__ b2,
    const unsigned short* __restrict__ Wut,
    const float* __restrict__ bu,
    const float* __restrict__ x,
    float* __restrict__ out)
{
    __shared__ __align__(16) unsigned short sW1[64 * SW1];   // 20992 B (node: sA)
    __shared__ __align__(16) float          sAcc[64 * SACC]; // 16640 B
    __shared__ __align__(16) unsigned char  sAH[4 * WAVE_LDS]; // 30720 B (node: sWu)
    __shared__ int   sdstoff[4 * 16];
    __shared__ float sdeg[64];

    const int t    = threadIdx.x;
    const int lane = t & 63;
    const int w    = t >> 6;
    const int b    = blockIdx.x;

    // ---- stage W1 + zero accumulators ----
    #pragma unroll
    for (int i = 0; i < 5; i++) {
        int c = t + i * 256;
        int n = c / 20, k8 = c % 20;
        *(u16x8*)&sW1[n * SW1 + k8 * 8] = *(const u16x8*)&W1t[c * 8];
    }
    for (int i = t; i < 64 * SACC; i += 256) sAcc[i] = 0.0f;
    if (t < 64) sdeg[t] = 0.0f;
    __syncthreads();

    unsigned short* myAin = (unsigned short*)(sAH + w * WAVE_LDS);
    unsigned short* myH   = (unsigned short*)(sAH + w * WAVE_LDS + 16 * SA * 2);

    if (lane < 16) {                     // zero the K-pad once
        u16x8 z = {0,0,0,0,0,0,0,0};
        *(u16x8*)&myAin[lane * SA + 144] = z;
        *(u16x8*)&myAin[lane * SA + 152] = z;
    }

    const int col = lane & 15;
    const int kq  = lane >> 4;
    const int el  = lane >> 2;
    const int q   = lane & 3;

    // ---- per-lane constants ----
    float b1r[4], b2r[4];
    u16x8 w2f[8];
    #pragma unroll
    for (int ct = 0; ct < 4; ct++) {
        b1r[ct] = b1[ct * 16 + col];
        b2r[ct] = b2[ct * 16 + col];
        #pragma unroll
        for (int ks = 0; ks < 2; ks++)
            w2f[ks * 4 + ct] = *(const u16x8*)&W2t[(ct * 16 + col) * 64 + ks * 32 + kq * 8];
    }

    const int base = bofs[b];
    const int ecnt = bofs[b + 1] - base;
    const int ng   = (ecnt + 15) >> 4;

    // ---- prologue gather (group w); meta/ea_s padded so loads are unconditional ----
    unsigned int pk = meta[base + w * 16 + el];
    int srcc = (int)(pk & 0x1FFFF);
    int dstc = (int)(pk >> 17);
    const u16x8* ps = (const u16x8*)(xb + (size_t)srcc * 64);
    u16x8 gx0 = ps[2 * q], gx1 = ps[2 * q + 1];
    const u16x8* pd = (const u16x8*)(xb + (size_t)(b * 64 + dstc) * 64);
    u16x8 dx0 = pd[2 * q], dx1 = pd[2 * q + 1];
    u16x4 fe = *(const u16x4*)&ea_s[(size_t)(base + w * 16 + el) * 16 + q * 4];

    for (int g = w; g < ng; g += 4) {
        const int remv = ecnt - g * 16;
        const int rem  = remv < 16 ? remv : 16;

        // issue next group's meta (lands during commit+GEMM1)
        unsigned int pkN = meta[base + (g + 4) * 16 + el];

        // ---- commit current gather to LDS ----
        unsigned short* rowp = myAin + el * SA;
        *(u16x8*)(rowp + q * 16)          = gx0;
        *(u16x8*)(rowp + q * 16 + 8)      = gx1;
        *(u16x8*)(rowp + 64 + q * 16)     = dx0;
        *(u16x8*)(rowp + 64 + q * 16 + 8) = dx1;
        *(u16x4*)(rowp + 128 + q * 4)     = fe;
        if (q == 1) sdstoff[w * 16 + el] = dstc;
        if (q == 2 && el < rem) atomicAdd(&sdeg[dstc], 1.0f);
        __builtin_amdgcn_wave_barrier();

        // ---- issue NEXT gather (overlaps GEMM1+GEMM2) ----
        int srcN = (int)(pkN & 0x1FFFF);
        int dstN = (int)(pkN >> 17);
        const u16x8* psN = (const u16x8*)(xb + (size_t)srcN * 64);
        u16x8 gxN0 = psN[2 * q], gxN1 = psN[2 * q + 1];
        const u16x8* pdN = (const u16x8*)(xb + (size_t)(b * 64 + dstN) * 64);
        u16x8 dxN0 = pdN[2 * q], dxN1 = pdN[2 * q + 1];
        u16x4 feN = *(const u16x4*)&ea_s[(size_t)(base + (g + 4) * 16 + el) * 16 + q * 4];

        // ---- GEMM1: 16x160 @ 160x64 ----
        f32x4 acc[4] = {{0,0,0,0},{0,0,0,0},{0,0,0,0},{0,0,0,0}};
        #pragma unroll
        for (int ks = 0; ks < 5; ks++) {
            int ko = ks * 32 + kq * 8;
            bf16x8 a = lds_frag(&myAin[col * SA + ko]);
            #pragma unroll
            for (int ct = 0; ct < 4; ct++) {
                bf16x8 bb = lds_frag(&sW1[(ct * 16 + col) * SW1 + ko]);
                acc[ct] = __builtin_amdgcn_mfma_f32_16x16x32_bf16(a, bb, acc[ct], 0, 0, 0);
            }
        }
        #pragma unroll
        for (int ct = 0; ct < 4; ct++) {
            #pragma unroll
            for (int r = 0; r < 4; r++)
                myH[(kq * 4 + r) * SH + ct * 16 + col] =
                    f2bf(fmaxf(acc[ct][r] + b1r[ct], 0.0f));
        }
        __builtin_amdgcn_wave_barrier();

        // ---- GEMM2: 16x64 @ 64x64 (B in registers) ----
        f32x4 m[4] = {{0,0,0,0},{0,0,0,0},{0,0,0,0},{0,0,0,0}};
        #pragma unroll
        for (int ks = 0; ks < 2; ks++) {
            int ko = ks * 32 + kq * 8;
            bf16x8 a = lds_frag(&myH[col * SH + ko]);
            #pragma unroll
            for (int ct = 0; ct < 4; ct++)
                m[ct] = __builtin_amdgcn_mfma_f32_16x16x32_bf16(
                    a, __builtin_bit_cast(bf16x8, w2f[ks * 4 + ct]), m[ct], 0, 0, 0);
        }
        __builtin_amdgcn_wave_barrier();

        // ---- accumulate messages into fp32 LDS (masked pad rows) ----
        int dsto[4];
        #pragma unroll
        for (int r = 0; r < 4; r++) dsto[r] = sdstoff[w * 16 + kq * 4 + r];
        #pragma unroll
        for (int ct = 0; ct < 4; ct++) {
            #pragma unroll
            for (int r = 0; r < 4; r++) {
                if (kq * 4 + r < rem)
                    atomicAdd(&sAcc[dsto[r] * SACC + ct * 16 + col],
                              m[ct][r] + b2r[ct]);
            }
        }
        __builtin_amdgcn_wave_barrier();   // LDS reads done before next commit

        gx0 = gxN0; gx1 = gxN1; dx0 = dxN0; dx1 = dxN1; fe = feN; dstc = dstN;
    }

    // ================= node-update phase (fused node_kernel tile) =================
    __syncthreads();                       // all edge work + atomics done

    unsigned short* sWu_n = (unsigned short*)sAH;   // overlay wave buffers
    unsigned short* sA_n  = sW1;                    // overlay W1 (stride NSA)
    const int n0 = b * 64;

    #pragma unroll
    for (int i = 0; i < 4; i++) {
        int c = t + i * 256;
        int n = c / 16, k8 = c % 16;
        *(u16x8*)&sWu_n[n * NSA + k8 * 8] = *(const u16x8*)&Wut[c * 8];
    }
    {
        const int nl = t >> 2, qq = t & 3;
        const int n = n0 + nl;
        unsigned short* row = sA_n + nl * NSA;
        if (n < N_NODES) {
            const float4* px = (const float4*)(x + (size_t)n * 64);
            cvt16v(row + qq * 16, px[qq*4], px[qq*4+1], px[qq*4+2], px[qq*4+3]);
            float inv = 1.0f / (sdeg[nl] + 1e-6f);
            u16x8 r0, r1;
            #pragma unroll
            for (int j = 0; j < 8; j++) {
                r0[j] = f2bf(sAcc[nl * SACC + qq * 16 + j] * inv);
                r1[j] = f2bf(sAcc[nl * SACC + qq * 16 + 8 + j] * inv);
            }
            *(u16x8*)(row + 64 + qq * 16)     = r0;
            *(u16x8*)(row + 64 + qq * 16 + 8) = r1;
        } else {
            u16x8 z = {0,0,0,0,0,0,0,0};
            *(u16x8*)&row[qq * 16]          = z;
            *(u16x8*)&row[qq * 16 + 8]      = z;
            *(u16x8*)&row[64 + qq * 16]     = z;
            *(u16x8*)&row[64 + qq * 16 + 8] = z;
        }
    }
    __syncthreads();

    const int arow = w * 16 + col;
    f32x4 acc[4] = {{0,0,0,0},{0,0,0,0},{0,0,0,0},{0,0,0,0}};
    #pragma unroll
    for (int ks = 0; ks < 4; ks++) {
        int ko = ks * 32 + kq * 8;
        bf16x8 a = lds_frag(&sA_n[arow * NSA + ko]);
        #pragma unroll
        for (int ct = 0; ct < 4; ct++) {
            bf16x8 bb = lds_frag(&sWu_n[(ct * 16 + col) * NSA + ko]);
            acc[ct] = __builtin_amdgcn_mfma_f32_16x16x32_bf16(a, bb, acc[ct], 0, 0, 0);
        }
    }
    #pragma unroll
    for (int ct = 0; ct < 4; ct++) {
        float bb = bu[ct * 16 + col];
        #pragma unroll
        for (int r = 0; r < 4; r++) {
            int row = w * 16 + kq * 4 + r;
            int n = n0 + row;
            if (n < N_NODES) {
                int c2 = ct * 16 + col;
                float xa = x[(size_t)n * 64 + c2];          // exact fp32 residual
                out[(size_t)n * 64 + c2] = xa + fmaxf(acc[ct][r] + bb, 0.0f);
            }
        }
    }
}

extern "C" void kernel_launch(void* const* d_in, const int* in_sizes, int n_in,
                              void* d_out, int out_size, void* d_ws, size_t ws_size,
                              hipStream_t stream) {
    const float* x  = (const float*)d_in[0];
    const int*   ei = (const int*)  d_in[1];
    const float* ea = (const float*)d_in[2];
    const float* W1 = (const float*)d_in[3];
    const float* b1 = (const float*)d_in[4];
    const float* W2 = (const float*)d_in[5];
    const float* b2 = (const float*)d_in[6];
    const float* Wu = (const float*)d_in[7];
    const float* bu = (const float*)d_in[8];
    float* out = (float*)d_out;

    // workspace layout (~71 MB), 16B-aligned regions first
    unsigned int* meta = (unsigned int*)d_ws;                        // [E+128]
    unsigned short* ea_s = (unsigned short*)(meta + N_EDGES + 128);  // [E+128][16]
    unsigned short* W1t = ea_s + (size_t)(N_EDGES + 128) * 16;       // [64][160]
    unsigned short* W2t = W1t + 64 * 160;                            // [64][64]
    unsigned short* Wut = W2t + 64 * 64;                             // [64][128]
    unsigned short* xb  = Wut + 64 * 128;                            // [N+64][64]
    int* bhist = (int*)(xb + (size_t)(N_NODES + 64) * 64);           // [NBKT]
    int* bofs  = bhist + NBKT;                                       // [NBKT+1]
    int* bcur  = bofs + NBKT + 1;                                    // [NBKT]

    hipMemsetAsync(bhist, 0, NBKT * sizeof(int), stream);

    prep_kernel<<<512, 256, 0, stream>>>(W1, W2, Wu, x, ei, W1t, W2t, Wut, xb, bhist);
    bscan_kernel<<<1, 1024, 0, stream>>>(bhist, bofs, bcur);
    bfill_kernel<<<1024, 256, 0, stream>>>(ei, ea, bcur, meta, ea_s);
    bagg_kernel<<<NBKT, 256, 0, stream>>>(xb, ea_s, meta, bofs,
                                          W1t, W2t, b1, b2, Wut, bu, x, out);
}

// Round 6
// 929.659 us; speedup vs baseline: 1.6310x; 1.6310x over previous
//
#include <hip/hip_runtime.h>

#define N_NODES  100000
#define N_EDGES  1600000
#define NODE_DIM 64
#define EDGE_DIM 16
#define HIDDEN   64
#define N_GROUPS 100000          // 16-edge groups
#define EDGE_BLOCKS 1280         // 5 blocks/CU * 256 CUs resident

typedef __bf16 bf16x8 __attribute__((ext_vector_type(8)));
typedef unsigned short u16x8 __attribute__((ext_vector_type(8)));
typedef unsigned short u16x4 __attribute__((ext_vector_type(4)));
typedef unsigned int   u32x4 __attribute__((ext_vector_type(4)));
typedef float f32x4 __attribute__((ext_vector_type(4)));

__device__ __forceinline__ unsigned short f2bf(float f) {
    unsigned int u = __float_as_uint(f);
    u += 0x7FFFu + ((u >> 16) & 1u);          // RNE
    return (unsigned short)(u >> 16);
}

__device__ __forceinline__ float bf2f(unsigned short s) {
    return __uint_as_float((unsigned int)s << 16);
}

__device__ __forceinline__ bf16x8 lds_frag(const unsigned short* p) {
    return __builtin_bit_cast(bf16x8, *(const u16x8*)p);
}

__device__ __forceinline__ unsigned pk2(float lo, float hi) {
    return ((unsigned)f2bf(hi) << 16) | (unsigned)f2bf(lo);
}

__device__ __forceinline__ void cvt16v(unsigned short* dst,
                                       float4 f0, float4 f1, float4 f2, float4 f3) {
    u16x8 p0, p1;
    p0[0]=f2bf(f0.x); p0[1]=f2bf(f0.y); p0[2]=f2bf(f0.z); p0[3]=f2bf(f0.w);
    p0[4]=f2bf(f1.x); p0[5]=f2bf(f1.y); p0[6]=f2bf(f1.z); p0[7]=f2bf(f1.w);
    p1[0]=f2bf(f2.x); p1[1]=f2bf(f2.y); p1[2]=f2bf(f2.z); p1[3]=f2bf(f2.w);
    p1[4]=f2bf(f3.x); p1[5]=f2bf(f3.y); p1[6]=f2bf(f3.z); p1[7]=f2bf(f3.w);
    *(u16x8*)dst       = p0;
    *(u16x8*)(dst + 8) = p1;
}

__device__ __forceinline__ void cvt4v(unsigned short* dst, float4 f) {
    u16x4 p;
    p[0]=f2bf(f.x); p[1]=f2bf(f.y); p[2]=f2bf(f.z); p[3]=f2bf(f.w);
    *(u16x4*)dst = p;
}

// packed 2xbf16 atomic add
__device__ __forceinline__ void atomic_pk_add_bf16(unsigned short* p, unsigned int v) {
    asm volatile("global_atomic_pk_add_bf16 %0, %1, off"
                 :: "v"(p), "v"(v) : "memory");
}

// ---- prep: bf16 weights (transposed; b1 folded into W1t row k=144) + bf16 x ----
__global__ void prep_kernel(const float* __restrict__ W1, const float* __restrict__ b1,
                            const float* __restrict__ W2, const float* __restrict__ Wu,
                            const float* __restrict__ x,
                            unsigned short* __restrict__ W1t,   // [64][160]
                            unsigned short* __restrict__ W2t,   // [64][64]
                            unsigned short* __restrict__ Wut,   // [64][128]
                            unsigned short* __restrict__ xb)    // [N][64] bf16
{
    int t = blockIdx.x * 256 + threadIdx.x;
    int stride = gridDim.x * 256;
    for (int i = t; i < N_NODES * 64 / 4; i += stride) {
        float4 f = ((const float4*)x)[i];
        cvt4v(&xb[i * 4], f);
    }
    for (int i = t; i < 64 * 160; i += stride) {
        int n = i / 160, k = i % 160;
        float v = (k < 144) ? W1[k * 64 + n] : (k == 144 ? b1[n] : 0.0f);
        W1t[i] = f2bf(v);
    }
    for (int i = t; i < 64 * 64; i += stride) {
        int n = i / 64, k = i % 64;
        W2t[i] = f2bf(W2[k * 64 + n]);
    }
    for (int i = t; i < 64 * 128; i += stride) {
        int n = i / 128, k = i % 128;
        Wut[i] = f2bf(Wu[k * 64 + n]);
    }
}

// LDS strides (elems)
#define SW1 164
#define SW2 66

#define MFMA_BF16 __builtin_amdgcn_mfma_f32_16x16x32_bf16
#define BC(v) __builtin_bit_cast(bf16x8, v)

// ---- edge kernel: fully register-resident MFMA pipeline, zero per-wave LDS ----
__global__ __launch_bounds__(256, 5) void edge_kernel(
    const unsigned short* __restrict__ xb,
    const int*   __restrict__ ei,
    const float* __restrict__ ea,
    const unsigned short* __restrict__ W1t,
    const unsigned short* __restrict__ W2t,
    unsigned short* __restrict__ agg,   // [N][64] bf16 (pre-zeroed)
    float* __restrict__ cnt)            // [N] f32 (pre-zeroed)
{
    __shared__ __align__(16) unsigned short sW1[64 * SW1];
    __shared__ __align__(16) unsigned short sW2[64 * SW2];

    const int t    = threadIdx.x;
    const int lane = t & 63;
    const int w    = t >> 6;

    // ---- stage W1 with sigma column-permutation; tile ct, tile-row ii holds
    // ---- W1^T column c1 = (ii>>2)*8 + (ct&1)*32 + (ct>>1)*4 + (ii&3).
    #pragma unroll
    for (int i = 0; i < 5; i++) {
        int c = t + i * 256;                 // 0..1279 = 64 rows * 20 chunks
        int row16 = c / 20, chunk = c % 20;
        int ct = row16 >> 4, ii = row16 & 15;
        int srcRow = ((ii >> 2) << 3) + (ct & 1) * 32 + ((ct >> 1) << 2) + (ii & 3);
        *(u16x8*)&sW1[row16 * SW1 + chunk * 8] = *(const u16x8*)&W1t[srcRow * 160 + chunk * 8];
    }
    // ---- stage W2 (natural order) ----
    #pragma unroll
    for (int i = 0; i < 2; i++) {
        int c = t + i * 256;                 // 0..511 = 64 rows * 8 chunks
        int n = c >> 3, k8 = c & 7;
        *(u16x8*)&sW2[n * SW2 + k8 * 8] = *(const u16x8*)&W2t[n * 64 + k8 * 8];
    }
    __syncthreads();                         // only block-wide barrier

    const int col = lane & 15;
    const int kq  = lane >> 4;

    // pad fragment for GEMM1 ks=4, kq>=2: k=144 must be 1.0 (b1 row); rest zero
    u16x8 padf = {0,0,0,0,0,0,0,0};
    if (kq == 2) padf[0] = 0x3F80;           // bf16 1.0

    const int TW = EDGE_BLOCKS * 4;
    int g = blockIdx.x * 4 + w;              // < 5120 < N_GROUPS

    // ---- prologue: group g's ei + gathers, group g+TW's ei ----
    int eiv  = ei[g * 16 + col + ((lane & 16) ? N_EDGES : 0)];
    int srcI = __shfl(eiv, col);
    int dstI = __shfl(eiv, 16 + col);
    const u16x8* ps = (const u16x8*)(xb + (size_t)srcI * 64);
    u16x8 sf0 = ps[kq], sf1 = ps[4 + kq];
    const u16x8* pd = (const u16x8*)(xb + (size_t)dstI * 64);
    u16x8 df0 = pd[kq], df1 = pd[4 + kq];
    float4 ea0 = {0,0,0,0}, ea1 = {0,0,0,0};
    if (kq < 2) {
        const float4* pe = (const float4*)(ea + ((size_t)g * 16 + col) * 16 + kq * 8);
        ea0 = pe[0]; ea1 = pe[1];
    }
    int gn  = g + TW;
    int gln = (gn < N_GROUPS) ? gn : g;      // clamped
    int eivN = ei[gln * 16 + col + ((lane & 16) ? N_EDGES : 0)];

    for (;;) {
        // ---- resolve next group's addresses; issue its gathers (cover = this GEMM) ----
        int srcN = __shfl(eivN, col);
        int dstN = __shfl(eivN, 16 + col);
        const u16x8* psN = (const u16x8*)(xb + (size_t)srcN * 64);
        u16x8 sfN0 = psN[kq], sfN1 = psN[4 + kq];
        const u16x8* pdN = (const u16x8*)(xb + (size_t)dstN * 64);
        u16x8 dfN0 = pdN[kq], dfN1 = pdN[4 + kq];
        float4 eaN0 = {0,0,0,0}, eaN1 = {0,0,0,0};
        if (kq < 2) {
            const float4* pe = (const float4*)(ea + ((size_t)gln * 16 + col) * 16 + kq * 8);
            eaN0 = pe[0]; eaN1 = pe[1];
        }
        int gn2  = gn + TW;
        int gln2 = (gn2 < N_GROUPS) ? gn2 : gln;
        int eivN2 = ei[gln2 * 16 + col + ((lane & 16) ? N_EDGES : 0)];

        // ---- current ea fragment (bf16) ----
        u16x8 ef;
        ef[0]=f2bf(ea0.x); ef[1]=f2bf(ea0.y); ef[2]=f2bf(ea0.z); ef[3]=f2bf(ea0.w);
        ef[4]=f2bf(ea1.x); ef[5]=f2bf(ea1.y); ef[6]=f2bf(ea1.z); ef[7]=f2bf(ea1.w);
        u16x8 b4u = (kq < 2) ? ef : padf;

        // ---- GEMM1-T: H^T = W1^T(perm) @ Ain^T ; b1 via k=144 ----
        f32x4 a0={0,0,0,0}, a1={0,0,0,0}, a2={0,0,0,0}, a3={0,0,0,0};
        #define G1STEP(KS, BB)                                                        \
        {   int ko = (KS) * 32 + kq * 8;                                              \
            a0 = MFMA_BF16(lds_frag(&sW1[( 0 + col) * SW1 + ko]), BC(BB), a0, 0,0,0); \
            a1 = MFMA_BF16(lds_frag(&sW1[(16 + col) * SW1 + ko]), BC(BB), a1, 0,0,0); \
            a2 = MFMA_BF16(lds_frag(&sW1[(32 + col) * SW1 + ko]), BC(BB), a2, 0,0,0); \
            a3 = MFMA_BF16(lds_frag(&sW1[(48 + col) * SW1 + ko]), BC(BB), a3, 0,0,0); \
        }
        G1STEP(0, sf0)
        G1STEP(1, sf1)
        G1STEP(2, df0)
        G1STEP(3, df1)
        G1STEP(4, b4u)
        #undef G1STEP

        // ---- relu + pack; sigma makes this directly GEMM2's B-fragments ----
        unsigned p0 = pk2(fmaxf(a0[0],0.f), fmaxf(a0[1],0.f));
        unsigned p1 = pk2(fmaxf(a0[2],0.f), fmaxf(a0[3],0.f));
        unsigned p2 = pk2(fmaxf(a1[0],0.f), fmaxf(a1[1],0.f));
        unsigned p3 = pk2(fmaxf(a1[2],0.f), fmaxf(a1[3],0.f));
        unsigned p4 = pk2(fmaxf(a2[0],0.f), fmaxf(a2[1],0.f));
        unsigned p5 = pk2(fmaxf(a2[2],0.f), fmaxf(a2[3],0.f));
        unsigned p6 = pk2(fmaxf(a3[0],0.f), fmaxf(a3[1],0.f));
        unsigned p7 = pk2(fmaxf(a3[2],0.f), fmaxf(a3[3],0.f));
        u32x4 h0v = {p0, p1, p4, p5};        // ks2=0: c1 = kq*8 + 0..7
        u32x4 h1v = {p2, p3, p6, p7};        // ks2=1: c1 = 32 + kq*8 + 0..7
        bf16x8 hf0 = __builtin_bit_cast(bf16x8, h0v);
        bf16x8 hf1 = __builtin_bit_cast(bf16x8, h1v);

        // ---- GEMM2-T: M^T = W2^T @ H^T (b2 deferred to node kernel) ----
        f32x4 m0={0,0,0,0}, m1={0,0,0,0}, m2={0,0,0,0}, m3={0,0,0,0};
        {
            int ko = kq * 8;
            m0 = MFMA_BF16(lds_frag(&sW2[( 0 + col) * SW2 + ko]), hf0, m0, 0,0,0);
            m1 = MFMA_BF16(lds_frag(&sW2[(16 + col) * SW2 + ko]), hf0, m1, 0,0,0);
            m2 = MFMA_BF16(lds_frag(&sW2[(32 + col) * SW2 + ko]), hf0, m2, 0,0,0);
            m3 = MFMA_BF16(lds_frag(&sW2[(48 + col) * SW2 + ko]), hf0, m3, 0,0,0);
            ko += 32;
            m0 = MFMA_BF16(lds_frag(&sW2[( 0 + col) * SW2 + ko]), hf1, m0, 0,0,0);
            m1 = MFMA_BF16(lds_frag(&sW2[(16 + col) * SW2 + ko]), hf1, m1, 0,0,0);
            m2 = MFMA_BF16(lds_frag(&sW2[(32 + col) * SW2 + ko]), hf1, m2, 0,0,0);
            m3 = MFMA_BF16(lds_frag(&sW2[(48 + col) * SW2 + ko]), hf1, m3, 0,0,0);
        }

        // ---- scatter: M^T lane layout = edge col, c2 = ct2*16 + kq*4 + r ----
        unsigned short* bp = agg + (size_t)dstI * 64 + kq * 4;
        atomic_pk_add_bf16(bp +  0, pk2(m0[0], m0[1]));
        atomic_pk_add_bf16(bp +  2, pk2(m0[2], m0[3]));
        atomic_pk_add_bf16(bp + 16, pk2(m1[0], m1[1]));
        atomic_pk_add_bf16(bp + 18, pk2(m1[2], m1[3]));
        atomic_pk_add_bf16(bp + 32, pk2(m2[0], m2[1]));
        atomic_pk_add_bf16(bp + 34, pk2(m2[2], m2[3]));
        atomic_pk_add_bf16(bp + 48, pk2(m3[0], m3[1]));
        atomic_pk_add_bf16(bp + 50, pk2(m3[2], m3[3]));
        if (lane < 16) atomicAdd(&cnt[dstI], 1.0f);

        if (gn >= N_GROUPS) break;
        // ---- rotate pipeline ----
        g = gn; gn = gn2; gln = gln2;
        sf0 = sfN0; sf1 = sfN1; df0 = dfN0; df1 = dfN1;
        ea0 = eaN0; ea1 = eaN1; dstI = dstN;
        eiv = eivN; eivN = eivN2;
    }
}

// ---- node update: [64 nodes x 128] x [128 x 64] per block; b2 added here ----
#define NSA 136
__global__ __launch_bounds__(256, 4) void node_kernel(
    const float* __restrict__ x,
    const unsigned short* __restrict__ agg,   // bf16 sums (no b2)
    const float* __restrict__ cnt,
    const unsigned short* __restrict__ Wut,
    const float* __restrict__ bu,
    const float* __restrict__ b2,
    float* __restrict__ out)
{
    __shared__ __align__(16) unsigned short sA [64 * NSA];
    __shared__ __align__(16) unsigned short sWu[64 * NSA];
    const int t = threadIdx.x, lane = t & 63, w = t >> 6;
    const int n0 = blockIdx.x * 64;

    #pragma unroll
    for (int i = 0; i < 4; i++) {
        int c = t + i * 256;
        int n = c / 16, k8 = c % 16;
        *(u16x8*)&sWu[n * NSA + k8 * 8] = *(const u16x8*)&Wut[c * 8];
    }
    {
        const int nl = t >> 2, q = t & 3;
        const int n = n0 + nl;
        unsigned short* row = sA + nl * NSA;
        if (n < N_NODES) {
            const float4* px = (const float4*)(x + (size_t)n * 64);
            cvt16v(row + q * 16, px[q*4], px[q*4+1], px[q*4+2], px[q*4+3]);
            float cv  = cnt[n];
            float inv = 1.0f / (cv + 1e-6f);
            float hasb = (cv > 0.5f) ? 1.0f : 0.0f;
            const u16x8* pa = (const u16x8*)(agg + (size_t)n * 64);
            u16x8 a0 = pa[2 * q], a1 = pa[2 * q + 1];
            u16x8 r0, r1;
            #pragma unroll
            for (int j = 0; j < 8; j++) {
                r0[j] = f2bf(bf2f(a0[j]) * inv + hasb * b2[q * 16 + j]);
                r1[j] = f2bf(bf2f(a1[j]) * inv + hasb * b2[q * 16 + 8 + j]);
            }
            *(u16x8*)(row + 64 + q * 16)     = r0;
            *(u16x8*)(row + 64 + q * 16 + 8) = r1;
        } else {
            u16x8 z = {0,0,0,0,0,0,0,0};
            *(u16x8*)&row[q * 16]          = z;
            *(u16x8*)&row[q * 16 + 8]      = z;
            *(u16x8*)&row[64 + q * 16]     = z;
            *(u16x8*)&row[64 + q * 16 + 8] = z;
        }
    }
    __syncthreads();

    const int col = lane & 15, kq = lane >> 4;
    const int arow = w * 16 + col;
    f32x4 acc[4] = {{0,0,0,0},{0,0,0,0},{0,0,0,0},{0,0,0,0}};
    #pragma unroll
    for (int ks = 0; ks < 4; ks++) {
        int ko = ks * 32 + kq * 8;
        bf16x8 a = lds_frag(&sA[arow * NSA + ko]);
        #pragma unroll
        for (int ct = 0; ct < 4; ct++) {
            bf16x8 b = lds_frag(&sWu[(ct * 16 + col) * NSA + ko]);
            acc[ct] = MFMA_BF16(a, b, acc[ct], 0, 0, 0);
        }
    }
    #pragma unroll
    for (int ct = 0; ct < 4; ct++) {
        float bb = bu[ct * 16 + col];
        #pragma unroll
        for (int r = 0; r < 4; r++) {
            int row = w * 16 + kq * 4 + r;
            int n = n0 + row;
            if (n < N_NODES) {
                int c2 = ct * 16 + col;
                float xa = x[(size_t)n * 64 + c2];          // exact fp32 residual
                out[(size_t)n * 64 + c2] = xa + fmaxf(acc[ct][r] + bb, 0.0f);
            }
        }
    }
}

extern "C" void kernel_launch(void* const* d_in, const int* in_sizes, int n_in,
                              void* d_out, int out_size, void* d_ws, size_t ws_size,
                              hipStream_t stream) {
    const float* x  = (const float*)d_in[0];
    const int*   ei = (const int*)  d_in[1];
    const float* ea = (const float*)d_in[2];
    const float* W1 = (const float*)d_in[3];
    const float* b1 = (const float*)d_in[4];
    const float* W2 = (const float*)d_in[5];
    const float* b2 = (const float*)d_in[6];
    const float* Wu = (const float*)d_in[7];
    const float* bu = (const float*)d_in[8];
    float* out = (float*)d_out;

    // workspace (~40 MB)
    unsigned short* agg = (unsigned short*)d_ws;                 // [N][64] bf16
    float* cnt = (float*)(agg + (size_t)N_NODES * HIDDEN);       // [N] f32
    unsigned short* W1t = (unsigned short*)(cnt + N_NODES);      // [64][160]
    unsigned short* W2t = W1t + 64 * 160;                        // [64][64]
    unsigned short* Wut = W2t + 64 * 64;                         // [64][128]
    unsigned short* xb  = Wut + 64 * 128;                        // [N][64] bf16

    hipMemsetAsync(d_ws, 0,
                   (size_t)N_NODES * HIDDEN * sizeof(unsigned short)
                   + (size_t)N_NODES * sizeof(float), stream);

    prep_kernel<<<512, 256, 0, stream>>>(W1, b1, W2, Wu, x, W1t, W2t, Wut, xb);
    edge_kernel<<<EDGE_BLOCKS, 256, 0, stream>>>(xb, ei, ea, W1t, W2t, agg, cnt);
    node_kernel<<<(N_NODES + 63) / 64, 256, 0, stream>>>(x, agg, cnt, Wut, bu, b2, out);
}

// Round 7
// 565.331 us; speedup vs baseline: 2.6821x; 1.6445x over previous
//
#include <hip/hip_runtime.h>

#define N_NODES  100000
#define N_EDGES  1600000
#define NODE_DIM 64
#define EDGE_DIM 16
#define HIDDEN   64
#define N_GROUPS 100000          // 16-edge groups
#define EDGE_BLOCKS 1024         // 4 blocks/CU * 256 CUs resident

typedef __bf16 bf16x8 __attribute__((ext_vector_type(8)));
typedef unsigned short u16x8 __attribute__((ext_vector_type(8)));
typedef unsigned short u16x4 __attribute__((ext_vector_type(4)));
typedef unsigned int   u32x4 __attribute__((ext_vector_type(4)));
typedef float f32x4 __attribute__((ext_vector_type(4)));

__device__ __forceinline__ unsigned short f2bf(float f) {
    unsigned int u = __float_as_uint(f);
    u += 0x7FFFu + ((u >> 16) & 1u);          // RNE
    return (unsigned short)(u >> 16);
}

__device__ __forceinline__ float bf2f(unsigned short s) {
    return __uint_as_float((unsigned int)s << 16);
}

__device__ __forceinline__ bf16x8 lds_frag(const unsigned short* p) {
    return __builtin_bit_cast(bf16x8, *(const u16x8*)p);
}

__device__ __forceinline__ unsigned pk2(float lo, float hi) {
    return ((unsigned)f2bf(hi) << 16) | (unsigned)f2bf(lo);
}

__device__ __forceinline__ void cvt16v(unsigned short* dst,
                                       float4 f0, float4 f1, float4 f2, float4 f3) {
    u16x8 p0, p1;
    p0[0]=f2bf(f0.x); p0[1]=f2bf(f0.y); p0[2]=f2bf(f0.z); p0[3]=f2bf(f0.w);
    p0[4]=f2bf(f1.x); p0[5]=f2bf(f1.y); p0[6]=f2bf(f1.z); p0[7]=f2bf(f1.w);
    p1[0]=f2bf(f2.x); p1[1]=f2bf(f2.y); p1[2]=f2bf(f2.z); p1[3]=f2bf(f2.w);
    p1[4]=f2bf(f3.x); p1[5]=f2bf(f3.y); p1[6]=f2bf(f3.z); p1[7]=f2bf(f3.w);
    *(u16x8*)dst       = p0;
    *(u16x8*)(dst + 8) = p1;
}

__device__ __forceinline__ void cvt4v(unsigned short* dst, float4 f) {
    u16x4 p;
    p[0]=f2bf(f.x); p[1]=f2bf(f.y); p[2]=f2bf(f.z); p[3]=f2bf(f.w);
    *(u16x4*)dst = p;
}

// packed 2xbf16 atomic add
__device__ __forceinline__ void atomic_pk_add_bf16(unsigned short* p, unsigned int v) {
    asm volatile("global_atomic_pk_add_bf16 %0, %1, off"
                 :: "v"(p), "v"(v) : "memory");
}

// ---- prep: bf16 weights (b1 folded into W1t row k=144) + bf16 x + degree ----
__global__ void prep_kernel(const float* __restrict__ W1, const float* __restrict__ b1,
                            const float* __restrict__ W2, const float* __restrict__ Wu,
                            const float* __restrict__ x, const int* __restrict__ ei,
                            unsigned short* __restrict__ W1t,   // [64][160]
                            unsigned short* __restrict__ W2t,   // [64][64]
                            unsigned short* __restrict__ Wut,   // [64][128]
                            unsigned short* __restrict__ xb,    // [N][64] bf16
                            int* __restrict__ deg)              // [N] (pre-zeroed)
{
    int t = blockIdx.x * 256 + threadIdx.x;
    int stride = gridDim.x * 256;
    for (int i = t; i < N_NODES * 64 / 4; i += stride) {
        float4 f = ((const float4*)x)[i];
        cvt4v(&xb[i * 4], f);
    }
    for (int e = t; e < N_EDGES; e += stride)
        atomicAdd(&deg[ei[N_EDGES + e]], 1);
    for (int i = t; i < 64 * 160; i += stride) {
        int n = i / 160, k = i % 160;
        float v = (k < 144) ? W1[k * 64 + n] : (k == 144 ? b1[n] : 0.0f);
        W1t[i] = f2bf(v);
    }
    for (int i = t; i < 64 * 64; i += stride) {
        int n = i / 64, k = i % 64;
        W2t[i] = f2bf(W2[k * 64 + n]);
    }
    for (int i = t; i < 64 * 128; i += stride) {
        int n = i / 128, k = i % 128;
        Wut[i] = f2bf(Wu[k * 64 + n]);
    }
}

// LDS strides (elems)
#define SW1 164
#define SW2 66
#define SMSG 34                  // u32 stride per edge row (even: b64-aligned; 2-way read free)

#define MFMA_BF16 __builtin_amdgcn_mfma_f32_16x16x32_bf16
#define BC(v) __builtin_bit_cast(bf16x8, v)

// ---- edge kernel: register GEMM pipeline + line-coalesced LDS-staged scatter ----
__global__ __launch_bounds__(256, 4) void edge_kernel(
    const unsigned short* __restrict__ xb,
    const int*   __restrict__ ei,
    const float* __restrict__ ea,
    const unsigned short* __restrict__ W1t,
    const unsigned short* __restrict__ W2t,
    unsigned short* __restrict__ agg)   // [N][64] bf16 (pre-zeroed)
{
    __shared__ __align__(16) unsigned short sW1[64 * SW1];           // 20992 B
    __shared__ __align__(16) unsigned short sW2[64 * SW2];           //  8448 B
    __shared__ __align__(16) unsigned int   sMsg[4][16][SMSG];       //  8704 B

    const int t    = threadIdx.x;
    const int lane = t & 63;
    const int w    = t >> 6;

    // ---- stage W1 with sigma column-permutation; tile ct, tile-row ii holds
    // ---- W1^T column c1 = (ii>>2)*8 + (ct&1)*32 + (ct>>1)*4 + (ii&3).
    #pragma unroll
    for (int i = 0; i < 5; i++) {
        int c = t + i * 256;                 // 0..1279 = 64 rows * 20 chunks
        int row16 = c / 20, chunk = c % 20;
        int ct = row16 >> 4, ii = row16 & 15;
        int srcRow = ((ii >> 2) << 3) + (ct & 1) * 32 + ((ct >> 1) << 2) + (ii & 3);
        *(u16x8*)&sW1[row16 * SW1 + chunk * 8] = *(const u16x8*)&W1t[srcRow * 160 + chunk * 8];
    }
    // ---- stage W2 (natural order) ----
    #pragma unroll
    for (int i = 0; i < 2; i++) {
        int c = t + i * 256;                 // 0..511 = 64 rows * 8 chunks
        int n = c >> 3, k8 = c & 7;
        *(u16x8*)&sW2[n * SW2 + k8 * 8] = *(const u16x8*)&W2t[n * 64 + k8 * 8];
    }
    __syncthreads();                         // only block-wide barrier

    const int col = lane & 15;
    const int kq  = lane >> 4;
    const int eh  = lane >> 5;
    const int c2  = lane & 31;

    // pad fragment for GEMM1 ks=4, kq>=2: k=144 must be 1.0 (b1 row); rest zero
    u16x8 padf = {0,0,0,0,0,0,0,0};
    if (kq == 2) padf[0] = 0x3F80;           // bf16 1.0

    const int TW = EDGE_BLOCKS * 4;
    int g = blockIdx.x * 4 + w;              // < 4096 < N_GROUPS

    // ---- prologue: group g's ei + gathers, group g+TW's ei ----
    int eiv  = ei[g * 16 + col + ((lane & 16) ? N_EDGES : 0)];
    int srcI = __shfl(eiv, col);
    int dstI = __shfl(eiv, 16 + col);
    const u16x8* ps = (const u16x8*)(xb + (size_t)srcI * 64);
    u16x8 sf0 = ps[kq], sf1 = ps[4 + kq];
    const u16x8* pd = (const u16x8*)(xb + (size_t)dstI * 64);
    u16x8 df0 = pd[kq], df1 = pd[4 + kq];
    float4 ea0 = {0,0,0,0}, ea1 = {0,0,0,0};
    if (kq < 2) {
        const float4* pe = (const float4*)(ea + ((size_t)g * 16 + col) * 16 + kq * 8);
        ea0 = pe[0]; ea1 = pe[1];
    }
    int gn  = g + TW;
    int gln = (gn < N_GROUPS) ? gn : g;      // clamped
    int eivN = ei[gln * 16 + col + ((lane & 16) ? N_EDGES : 0)];

    for (;;) {
        // ---- resolve next group's addresses; issue its gathers (cover = this GEMM) ----
        int srcN = __shfl(eivN, col);
        int dstN = __shfl(eivN, 16 + col);
        const u16x8* psN = (const u16x8*)(xb + (size_t)srcN * 64);
        u16x8 sfN0 = psN[kq], sfN1 = psN[4 + kq];
        const u16x8* pdN = (const u16x8*)(xb + (size_t)dstN * 64);
        u16x8 dfN0 = pdN[kq], dfN1 = pdN[4 + kq];
        float4 eaN0 = {0,0,0,0}, eaN1 = {0,0,0,0};
        if (kq < 2) {
            const float4* pe = (const float4*)(ea + ((size_t)gln * 16 + col) * 16 + kq * 8);
            eaN0 = pe[0]; eaN1 = pe[1];
        }
        int gn2  = gn + TW;
        int gln2 = (gn2 < N_GROUPS) ? gn2 : gln;
        int eivN2 = ei[gln2 * 16 + col + ((lane & 16) ? N_EDGES : 0)];

        // ---- current ea fragment (bf16) ----
        u16x8 ef;
        ef[0]=f2bf(ea0.x); ef[1]=f2bf(ea0.y); ef[2]=f2bf(ea0.z); ef[3]=f2bf(ea0.w);
        ef[4]=f2bf(ea1.x); ef[5]=f2bf(ea1.y); ef[6]=f2bf(ea1.z); ef[7]=f2bf(ea1.w);
        u16x8 b4u = (kq < 2) ? ef : padf;

        // ---- GEMM1-T: H^T = W1^T(perm) @ Ain^T ; b1 via k=144 ----
        f32x4 a0={0,0,0,0}, a1={0,0,0,0}, a2={0,0,0,0}, a3={0,0,0,0};
        #define G1STEP(KS, BB)                                                        \
        {   int ko = (KS) * 32 + kq * 8;                                              \
            a0 = MFMA_BF16(lds_frag(&sW1[( 0 + col) * SW1 + ko]), BC(BB), a0, 0,0,0); \
            a1 = MFMA_BF16(lds_frag(&sW1[(16 + col) * SW1 + ko]), BC(BB), a1, 0,0,0); \
            a2 = MFMA_BF16(lds_frag(&sW1[(32 + col) * SW1 + ko]), BC(BB), a2, 0,0,0); \
            a3 = MFMA_BF16(lds_frag(&sW1[(48 + col) * SW1 + ko]), BC(BB), a3, 0,0,0); \
        }
        G1STEP(0, sf0)
        G1STEP(1, sf1)
        G1STEP(2, df0)
        G1STEP(3, df1)
        G1STEP(4, b4u)
        #undef G1STEP

        // ---- relu + pack; sigma makes this directly GEMM2's B-fragments ----
        unsigned p0 = pk2(fmaxf(a0[0],0.f), fmaxf(a0[1],0.f));
        unsigned p1 = pk2(fmaxf(a0[2],0.f), fmaxf(a0[3],0.f));
        unsigned p2 = pk2(fmaxf(a1[0],0.f), fmaxf(a1[1],0.f));
        unsigned p3 = pk2(fmaxf(a1[2],0.f), fmaxf(a1[3],0.f));
        unsigned p4 = pk2(fmaxf(a2[0],0.f), fmaxf(a2[1],0.f));
        unsigned p5 = pk2(fmaxf(a2[2],0.f), fmaxf(a2[3],0.f));
        unsigned p6 = pk2(fmaxf(a3[0],0.f), fmaxf(a3[1],0.f));
        unsigned p7 = pk2(fmaxf(a3[2],0.f), fmaxf(a3[3],0.f));
        u32x4 h0v = {p0, p1, p4, p5};        // ks2=0: c1 = kq*8 + 0..7
        u32x4 h1v = {p2, p3, p6, p7};        // ks2=1: c1 = 32 + kq*8 + 0..7
        bf16x8 hf0 = __builtin_bit_cast(bf16x8, h0v);
        bf16x8 hf1 = __builtin_bit_cast(bf16x8, h1v);

        // ---- GEMM2-T: M^T = W2^T @ H^T (b2 deferred to node kernel) ----
        f32x4 m0={0,0,0,0}, m1={0,0,0,0}, m2={0,0,0,0}, m3={0,0,0,0};
        {
            int ko = kq * 8;
            m0 = MFMA_BF16(lds_frag(&sW2[( 0 + col) * SW2 + ko]), hf0, m0, 0,0,0);
            m1 = MFMA_BF16(lds_frag(&sW2[(16 + col) * SW2 + ko]), hf0, m1, 0,0,0);
            m2 = MFMA_BF16(lds_frag(&sW2[(32 + col) * SW2 + ko]), hf0, m2, 0,0,0);
            m3 = MFMA_BF16(lds_frag(&sW2[(48 + col) * SW2 + ko]), hf0, m3, 0,0,0);
            ko += 32;
            m0 = MFMA_BF16(lds_frag(&sW2[( 0 + col) * SW2 + ko]), hf1, m0, 0,0,0);
            m1 = MFMA_BF16(lds_frag(&sW2[(16 + col) * SW2 + ko]), hf1, m1, 0,0,0);
            m2 = MFMA_BF16(lds_frag(&sW2[(32 + col) * SW2 + ko]), hf1, m2, 0,0,0);
            m3 = MFMA_BF16(lds_frag(&sW2[(48 + col) * SW2 + ko]), hf1, m3, 0,0,0);
        }

        // ---- stage M^T to LDS: edge row = col; u32 slot ct2*8+kq*2+{0,1} = cols/2 ----
        sMsg[w][col][      kq * 2    ] = pk2(m0[0], m0[1]);
        sMsg[w][col][      kq * 2 + 1] = pk2(m0[2], m0[3]);
        sMsg[w][col][ 8  + kq * 2    ] = pk2(m1[0], m1[1]);
        sMsg[w][col][ 8  + kq * 2 + 1] = pk2(m1[2], m1[3]);
        sMsg[w][col][16  + kq * 2    ] = pk2(m2[0], m2[1]);
        sMsg[w][col][16  + kq * 2 + 1] = pk2(m2[2], m2[3]);
        sMsg[w][col][24  + kq * 2    ] = pk2(m3[0], m3[1]);
        sMsg[w][col][24  + kq * 2 + 1] = pk2(m3[2], m3[3]);
        __builtin_amdgcn_wave_barrier();

        // ---- scatter: 2 edges/instr, lanes 0-31 contiguous over one 128B row ----
        #pragma unroll 1
        for (int i = 0; i < 8; i++) {
            int el2 = i * 2 + eh;
            int dd  = __shfl(eiv, 16 + el2);
            unsigned pkv = sMsg[w][el2][c2];
            atomic_pk_add_bf16(&agg[(size_t)dd * 64 + c2 * 2], pkv);
        }
        __builtin_amdgcn_wave_barrier();     // reads done before next overwrite

        if (gn >= N_GROUPS) break;
        // ---- rotate pipeline ----
        g = gn; gn = gn2; gln = gln2;
        sf0 = sfN0; sf1 = sfN1; df0 = dfN0; df1 = dfN1;
        ea0 = eaN0; ea1 = eaN1; dstI = dstN;
        eiv = eivN; eivN = eivN2;
    }
}

// ---- node update: [64 nodes x 128] x [128 x 64] per block; b2 added here ----
#define NSA 136
__global__ __launch_bounds__(256, 4) void node_kernel(
    const float* __restrict__ x,
    const unsigned short* __restrict__ agg,   // bf16 sums (no b2)
    const int* __restrict__ deg,
    const unsigned short* __restrict__ Wut,
    const float* __restrict__ bu,
    const float* __restrict__ b2,
    float* __restrict__ out)
{
    __shared__ __align__(16) unsigned short sA [64 * NSA];
    __shared__ __align__(16) unsigned short sWu[64 * NSA];
    const int t = threadIdx.x, lane = t & 63, w = t >> 6;
    const int n0 = blockIdx.x * 64;

    #pragma unroll
    for (int i = 0; i < 4; i++) {
        int c = t + i * 256;
        int n = c / 16, k8 = c % 16;
        *(u16x8*)&sWu[n * NSA + k8 * 8] = *(const u16x8*)&Wut[c * 8];
    }
    {
        const int nl = t >> 2, q = t & 3;
        const int n = n0 + nl;
        unsigned short* row = sA + nl * NSA;
        if (n < N_NODES) {
            const float4* px = (const float4*)(x + (size_t)n * 64);
            cvt16v(row + q * 16, px[q*4], px[q*4+1], px[q*4+2], px[q*4+3]);
            float cv  = (float)deg[n];
            float inv = 1.0f / (cv + 1e-6f);
            float hasb = (cv > 0.5f) ? 1.0f : 0.0f;
            const u16x8* pa = (const u16x8*)(agg + (size_t)n * 64);
            u16x8 a0 = pa[2 * q], a1 = pa[2 * q + 1];
            u16x8 r0, r1;
            #pragma unroll
            for (int j = 0; j < 8; j++) {
                r0[j] = f2bf(bf2f(a0[j]) * inv + hasb * b2[q * 16 + j]);
                r1[j] = f2bf(bf2f(a1[j]) * inv + hasb * b2[q * 16 + 8 + j]);
            }
            *(u16x8*)(row + 64 + q * 16)     = r0;
            *(u16x8*)(row + 64 + q * 16 + 8) = r1;
        } else {
            u16x8 z = {0,0,0,0,0,0,0,0};
            *(u16x8*)&row[q * 16]          = z;
            *(u16x8*)&row[q * 16 + 8]      = z;
            *(u16x8*)&row[64 + q * 16]     = z;
            *(u16x8*)&row[64 + q * 16 + 8] = z;
        }
    }
    __syncthreads();

    const int col = lane & 15, kq = lane >> 4;
    const int arow = w * 16 + col;
    f32x4 acc[4] = {{0,0,0,0},{0,0,0,0},{0,0,0,0},{0,0,0,0}};
    #pragma unroll
    for (int ks = 0; ks < 4; ks++) {
        int ko = ks * 32 + kq * 8;
        bf16x8 a = lds_frag(&sA[arow * NSA + ko]);
        #pragma unroll
        for (int ct = 0; ct < 4; ct++) {
            bf16x8 b = lds_frag(&sWu[(ct * 16 + col) * NSA + ko]);
            acc[ct] = MFMA_BF16(a, b, acc[ct], 0, 0, 0);
        }
    }
    #pragma unroll
    for (int ct = 0; ct < 4; ct++) {
        float bb = bu[ct * 16 + col];
        #pragma unroll
        for (int r = 0; r < 4; r++) {
            int row = w * 16 + kq * 4 + r;
            int n = n0 + row;
            if (n < N_NODES) {
                int c2 = ct * 16 + col;
                float xa = x[(size_t)n * 64 + c2];          // exact fp32 residual
                out[(size_t)n * 64 + c2] = xa + fmaxf(acc[ct][r] + bb, 0.0f);
            }
        }
    }
}

extern "C" void kernel_launch(void* const* d_in, const int* in_sizes, int n_in,
                              void* d_out, int out_size, void* d_ws, size_t ws_size,
                              hipStream_t stream) {
    const float* x  = (const float*)d_in[0];
    const int*   ei = (const int*)  d_in[1];
    const float* ea = (const float*)d_in[2];
    const float* W1 = (const float*)d_in[3];
    const float* b1 = (const float*)d_in[4];
    const float* W2 = (const float*)d_in[5];
    const float* b2 = (const float*)d_in[6];
    const float* Wu = (const float*)d_in[7];
    const float* bu = (const float*)d_in[8];
    float* out = (float*)d_out;

    // workspace (~40 MB)
    unsigned short* agg = (unsigned short*)d_ws;                 // [N][64] bf16
    int* deg = (int*)(agg + (size_t)N_NODES * HIDDEN);           // [N] int
    unsigned short* W1t = (unsigned short*)(deg + N_NODES);      // [64][160]
    unsigned short* W2t = W1t + 64 * 160;                        // [64][64]
    unsigned short* Wut = W2t + 64 * 64;                         // [64][128]
    unsigned short* xb  = Wut + 64 * 128;                        // [N][64] bf16

    hipMemsetAsync(d_ws, 0,
                   (size_t)N_NODES * HIDDEN * sizeof(unsigned short)
                   + (size_t)N_NODES * sizeof(int), stream);

    prep_kernel<<<512, 256, 0, stream>>>(W1, b1, W2, Wu, x, ei, W1t, W2t, Wut, xb, deg);
    edge_kernel<<<EDGE_BLOCKS, 256, 0, stream>>>(xb, ei, ea, W1t, W2t, agg);
    node_kernel<<<(N_NODES + 63) / 64, 256, 0, stream>>>(x, agg, deg, Wut, bu, b2, out);
}